// Round 7
// baseline (241.730 us; speedup 1.0000x reference)
//
#include <hip/hip_runtime.h>

#define B_ 64
#define T_ 1024
#define V_ 512
#define L_ 128
#define LOG2E_ 1.4426950408889634f
#define LN2_   0.6931471805599453f
#define C_ 48           // timestep rows per chunk (3 producer waves x 16 rows)
#define RW4_ 65         // ring row stride in f4 (260 floats, 1040 B) - proven conflict-free
#define NC_ ((T_ - 1 + C_ - 1) / C_)   // 22 chunks cover t = 1..1023

typedef float f4_t __attribute__((ext_vector_type(4)));

__device__ __forceinline__ float exp2_fast(float x) { return __builtin_amdgcn_exp2f(x); }
__device__ __forceinline__ float log2_fast(float x) { return __builtin_amdgcn_logf(x); }
__device__ __forceinline__ float ldx(float v, int e) { return __builtin_amdgcn_ldexpf(v, e); }

// wave shift-up-by-1 (lane i <- lane i-1): DPP wave_shr:1
// bound_ctrl=true -> lane0 gets 0; keep-variant -> lane0 keeps `old`
__device__ __forceinline__ float dpp_shr1_f(float x) {
    return __int_as_float(__builtin_amdgcn_update_dpp(0, __float_as_int(x), 0x138, 0xf, 0xf, true));
}
__device__ __forceinline__ int dpp_shr1_keep_i(int old, int x) {
    return __builtin_amdgcn_update_dpp(old, x, 0x138, 0xf, 0xf, false);
}
// bit-exact wave broadcast of a float (R5/R6 bug: passing float directly to
// readfirstlane applies implicit float->int TRUNCATION of the value)
__device__ __forceinline__ float bcast_first_f(float x) {
    return __int_as_float(__builtin_amdgcn_readfirstlane(__float_as_int(x)));
}

// One block (4 waves, 256 thr) per batch item — one wave per SIMD, so the
// serial consumer wave OWNS its SIMD's issue slots (R4 post-mortem: with 8
// waves the consumer shared a SIMD with a producer; ~130cyc/step of stall).
//  wave 0   : scaled LINEAR-domain alpha recursion — R4-exact step (own-shift
//             scale adoption). 4-deep e-prefetch ring; E-adoption via
//             bound_ctrl=false DPP (no cndmask on the chain).
//  waves1-3 : coalesced-ingest (2x b128/row, 32-deep MLP) + LDS-bounce
//             random-column select + pack (eb,e1,e3,pad) — R4-proven.
//             Blank col via BIT-EXACT readfirstlane broadcast.
// One __syncthreads per 48-row chunk, 2-buffer ping/pong.
__global__ __launch_bounds__(256, 1) void ctc_alpha_kernel(
    const float* __restrict__ outputs, const int* __restrict__ labels,
    const int* __restrict__ out_lens, const int* __restrict__ lab_lens,
    float* __restrict__ ws, float* __restrict__ out)
{
    const int b    = blockIdx.x;
    const int tid  = threadIdx.x;
    const int wid  = tid >> 6;
    const int lane = tid & 63;

    int* cnt = (int*)ws;            // ws[0]: zeroed by hipMemsetAsync each launch
    float* losses = ws + 16;        // ws[16..79]: per-batch losses

    __shared__ f4_t  ring4[2][C_ * RW4_];   // 2 x 48 x 1040 B = 99,840 B
    __shared__ f4_t  scr[3][2][129];        // 12,384 B raw-row scratch (2064 B/buf)
    __shared__ float save2[2];
    __shared__ int   saveE[2];
    __shared__ int   amLast;

    const int olen  = out_lens[b];
    const int ll    = lab_lens[b];
    const int s0q   = 2 * ll - 1;                 // odd
    const int s1q   = 2 * ll;                     // even, may be 256
    const int tlast = olen - 1;
    const int l0  = s0q >> 2, j0 = s0q & 3;
    const int l1e = (s1q == 256) ? 63 : (s1q >> 2);
    const int j1  = s1q & 3;
    const float* base = outputs + (size_t)b * T_ * V_;
    const int*   lab  = labels + b * L_;

    // per-lane label columns (consumer lane l's odd states)
    const int cA = lab[2 * lane];         // col for state 4l+1
    const int cB = lab[2 * lane + 1];     // col for state 4l+3

    // ---------------- consumer setup (wave 0) ----------------
    float sk1 = 0.f, sk3 = 0.f;
    float v0 = 0.f, v1 = 0.f, v2 = 0.f, v3 = 0.f, vx = 0.f;  // vx: state 256 (lane63)
    int   E = 0;                                             // per-lane scale
    const bool isl0 = (lane == 0);
    if (wid == 0) {
        __builtin_amdgcn_s_setprio(3);
        sk3 = (cB != cA) ? 1.f : 0.f;
        if (lane >= 1) sk1 = (cA != lab[2 * lane - 1]) ? 1.f : 0.f;
        if (isl0) {
            v0 = exp2_fast(base[0]      * LOG2E_);       // s=0 blank
            v1 = exp2_fast(base[lab[0]] * LOG2E_);       // s=1 first label
        }
        if (tlast == 0) {
            float w0 = (j0==0)?v0:(j0==1)?v1:(j0==2)?v2:v3;
            float w1 = (s1q==256) ? vx : ((j1==0)?v0:(j1==1)?v1:(j1==2)?v2:v3);
            if (lane == l0)  { save2[0] = w0; saveE[0] = E; }
            if (lane == l1e) { save2[1] = w1; saveE[1] = E; }
        }
    } else {
        __builtin_amdgcn_s_setprio(0);
    }

    // producer: coalesced-ingest + LDS-side select + pack.
    //  rows r = (wid-1) + 3*m, m = 0..15; all 32 b128 loads issue first (MLP).
    auto produce = [&](int bb, int t0) {
        const int w1 = wid - 1;
        f4_t A[16], Cc[16];
        #pragma unroll
        for (int m = 0; m < 16; ++m) {
            int t = t0 + w1 + 3 * m;
            const f4_t* rp = (const f4_t*)((t < T_) ? (base + (size_t)t * V_) : base);
            A[m]  = rp[lane];          // cols 4*lane   .. 4*lane+3
            Cc[m] = rp[lane + 64];     // cols 256+4*lane ..
        }
        scr[w1][0][lane]      = A[0];      // conflict-free: 16B/lane contiguous
        scr[w1][0][lane + 64] = Cc[0];
        #pragma unroll
        for (int m = 1; m <= 16; ++m) {
            if (m < 16) {
                scr[w1][m & 1][lane]      = A[m];
                scr[w1][m & 1][lane + 64] = Cc[m];
            }
            int r = w1 + 3 * (m - 1);
            int t = t0 + r;
            if (t < T_) {
                // blank col 0 = lane0's A.x: bit-exact broadcast
                float gb = bcast_first_f(A[m - 1].x);
                const float* sf = (const float*)&scr[w1][(m - 1) & 1][0];
                float g1 = sf[cA];     // scattered: conflicts land producer-side
                float g3 = sf[cB];
                f4_t e;
                e.x = exp2_fast(gb * LOG2E_);
                e.y = exp2_fast(g1 * LOG2E_);
                e.z = exp2_fast(g3 * LOG2E_);
                e.w = 0.f;
                ring4[bb][r * RW4_ + lane] = e;
            }
        }
    };

    // one recursion step with per-lane scale adoption (R4-exact own-shift form)
    auto step = [&](f4_t e) {
        float up1 = dpp_shr1_f(v3);           // state 4l-1 (lane0 -> 0)
        int   upE = dpp_shr1_keep_i(E, E);    // lane0 keeps own E (bound_ctrl=0)

        int d    = upE - E;
        int mpos = (d > 0) ? d : 0;           // max(d,0)
        int sin  = (d < 0) ? d : 0;           // min(d,0)
        int sown = -mpos;
        E += mpos;
        v0 = ldx(v0, sown); v1 = ldx(v1, sown); v2 = ldx(v2, sown);
        v3 = ldx(v3, sown); vx = ldx(vx, sown);
        up1 = ldx(up1, sin);

        float n0 = (v0 + up1) * e.x;                   // even: no skip, blank col
        float n1 = fmaf(sk1, up1, v1 + v0) * e.y;      // skip from 4l-1 = up1
        float n2 = (v2 + v1) * e.x;                    // even: no skip, blank col
        float n3 = fmaf(sk3, v1, v3 + v2) * e.z;       // skip from 4l+1 = v1
        vx = (vx + v3) * e.x;                          // state 256 (blank col too)
        v0 = n0; v1 = n1; v2 = n2; v3 = n3;
    };

    auto renorm = [&]() {
        float mx = fmaxf(fmaxf(v0, v1), fmaxf(v2, v3));
        mx = fmaxf(mx, vx);
        int ex = (__float_as_int(mx) >> 23) - 126;     // 0 lanes: ex = -126
        v0 = ldx(v0, -ex); v1 = ldx(v1, -ex); v2 = ldx(v2, -ex); v3 = ldx(v3, -ex);
        vx = ldx(vx, -ex);
        E += ex;
    };

    auto consume = [&](int bb, int t0) {
        const f4_t* rp4 = &ring4[bb][lane];
        // 4-deep period-4 prefetch ring; residues constant under unroll 8
        f4_t eb4[4];
        eb4[0] = rp4[0];
        eb4[1] = rp4[RW4_];
        eb4[2] = rp4[2 * RW4_];
        eb4[3] = rp4[3 * RW4_];

        bool chk = (t0 + C_ > T_) || ((unsigned)(tlast - t0) < (unsigned)C_);
        if (!chk) {
            #pragma unroll 8
            for (int r = 0; r < C_; ++r) {
                f4_t e = eb4[r & 3];
                if (r + 4 < C_) eb4[r & 3] = rp4[(r + 4) * RW4_];
                step(e);
                if ((r & 3) == 3) renorm();
            }
        } else {
            #pragma unroll 4
            for (int r = 0; r < C_; ++r) {
                int t = t0 + r;
                if (t >= T_) break;
                f4_t e = eb4[r & 3];
                if (r + 4 < C_) eb4[r & 3] = rp4[(r + 4) * RW4_];
                step(e);
                if ((r & 3) == 3) renorm();
                if (t == tlast) {
                    float w0 = (j0==0)?v0:(j0==1)?v1:(j0==2)?v2:v3;
                    float w1 = (s1q==256) ? vx : ((j1==0)?v0:(j1==1)?v1:(j1==2)?v2:v3);
                    if (lane == l0)  { save2[0] = w0; saveE[0] = E; }
                    if (lane == l1e) { save2[1] = w1; saveE[1] = E; }
                }
            }
        }
    };

    // ---------------- pipeline ----------------
    if (wid > 0) produce(0, 1);
    __syncthreads();
    for (int c = 0; c < NC_; ++c) {
        if (wid > 0) {
            if (c + 1 < NC_) produce((c + 1) & 1, 1 + (c + 1) * C_);
        } else {
            consume(c & 1, 1 + c * C_);
        }
        __syncthreads();
    }

    // ---------------- fused finish: per-batch loss + last-block mean ----------
    if (tid == 0) {
        float lx = log2_fast(save2[0]) + (float)saveE[0];
        float ly = log2_fast(save2[1]) + (float)saveE[1];
        float m  = fmaxf(lx, ly);
        float lik2 = m + log2_fast(exp2_fast(lx - m) + exp2_fast(ly - m));
        float loss = -(lik2 * LN2_) / (float)ll;
        __hip_atomic_store(&losses[b], loss, __ATOMIC_RELAXED, __HIP_MEMORY_SCOPE_AGENT);
        int old = __hip_atomic_fetch_add(cnt, 1, __ATOMIC_ACQ_REL, __HIP_MEMORY_SCOPE_AGENT);
        amLast = (old == B_ - 1);
    }
    __syncthreads();
    if (amLast && wid == 0) {
        float v = __hip_atomic_load(&losses[lane], __ATOMIC_RELAXED, __HIP_MEMORY_SCOPE_AGENT);
        #pragma unroll
        for (int o = 32; o > 0; o >>= 1) v += __shfl_down(v, o);
        if (lane == 0) out[0] = v * (1.0f / B_);
    }
}

extern "C" void kernel_launch(void* const* d_in, const int* in_sizes, int n_in,
                              void* d_out, int out_size, void* d_ws, size_t ws_size,
                              hipStream_t stream) {
    const float* outputs  = (const float*)d_in[0];
    const int*   labels   = (const int*)d_in[1];
    const int*   out_lens = (const int*)d_in[2];
    const int*   lab_lens = (const int*)d_in[3];

    (void)hipMemsetAsync(d_ws, 0, 64, stream);   // zero the completion counter
    ctc_alpha_kernel<<<B_, 256, 0, stream>>>(outputs, labels, out_lens, lab_lens,
                                             (float*)d_ws, (float*)d_out);
}

// Round 10
// 230.375 us; speedup vs baseline: 1.0493x; 1.0493x over previous
//
#include <hip/hip_runtime.h>

#define B_ 64
#define T_ 1024
#define V_ 512
#define L_ 128
#define LOG2E_ 1.4426950408889634f
#define LN2_   0.6931471805599453f
#define C_ 56           // timestep rows per chunk (7 producer waves x 8 rows)
#define RW4_ 65         // ring row stride in f4 (1040 B) - proven conflict-free
#define NC_ ((T_ - 1 + C_ - 1) / C_)   // 19 chunks cover t = 1..1023

typedef float f4_t __attribute__((ext_vector_type(4)));

__device__ __forceinline__ float exp2_fast(float x) { return __builtin_amdgcn_exp2f(x); }
__device__ __forceinline__ float log2_fast(float x) { return __builtin_amdgcn_logf(x); }
__device__ __forceinline__ float ldx(float v, int e) { return __builtin_amdgcn_ldexpf(v, e); }

// wave shift-up-by-1 (lane i <- lane i-1): DPP wave_shr:1
__device__ __forceinline__ float dpp_shr1_f(float x) {
    return __int_as_float(__builtin_amdgcn_update_dpp(0, __float_as_int(x), 0x138, 0xf, 0xf, true));
}
__device__ __forceinline__ int dpp_shr1_keep_i(int old, int x) {
    return __builtin_amdgcn_update_dpp(old, x, 0x138, 0xf, 0xf, false);
}
// bit-exact wave broadcast of a float (R5/R6 bug: float->int value truncation)
__device__ __forceinline__ float bcast_first_f(float x) {
    return __int_as_float(__builtin_amdgcn_readfirstlane(__float_as_int(x)));
}

// One block (8 waves) per batch item, R4's proven barrier ping-pong structure.
// (R8/R9 async-ring line abandoned: two hang-class failures; spin-loop flow
// control is unverifiable at this measurement cost.)
//  wave 0   : scaled LINEAR-domain alpha recursion.
//             - e-FOLD step: shift up1 once by d=upE-E and fold 2^sown into
//               the e multipliers. Bit-identical to own-shift (pow2 scaling
//               commutes with fp rounding; R5==R6 byte-identical outputs
//               proved equivalence empirically; up1!=0 with |d| huge is
//               impossible since v3 fills >=3 steps after first adoption).
//               Removes all 5 ldexps from the loop-carried v chain.
//             - 8-deep e-prefetch ring, static offsets (120cyc ds_read
//               latency fully covered at ~30cyc/step).
//  waves1-7 : chunk-level load-ahead (T14): during iter c, PACK chunk c+1
//             from regs loaded in iter c-1, issue LOADs for chunk c+2.
//             HBM latency retires across a whole chunk + barrier instead of
//             serializing inside the chunk behind the barrier. Bounce/select
//             identical to R4 (coalesced ingest -> LDS scratch -> random-col
//             select -> pack (eb,e1,e3,pad)); blank col via bit-exact
//             readfirstlane broadcast.
__global__ __launch_bounds__(512, 1) void ctc_alpha_kernel(
    const float* __restrict__ outputs, const int* __restrict__ labels,
    const int* __restrict__ out_lens, const int* __restrict__ lab_lens,
    float* __restrict__ ws, float* __restrict__ out)
{
    const int b    = blockIdx.x;
    const int tid  = threadIdx.x;
    const int wid  = tid >> 6;
    const int lane = tid & 63;

    int* cnt = (int*)ws;            // ws[0]: zeroed by hipMemsetAsync each launch
    float* losses = ws + 16;        // ws[16..79]: per-batch losses

    __shared__ f4_t  ring4[2][C_ * RW4_];   // 116,480 B
    __shared__ f4_t  scr[7][2][129];        //  28,896 B raw-row bounce scratch
    __shared__ float save2[2];
    __shared__ int   saveE[2];
    __shared__ int   amLast;

    const int olen  = out_lens[b];
    const int ll    = lab_lens[b];
    const int s0q   = 2 * ll - 1;                 // odd
    const int s1q   = 2 * ll;                     // even, may be 256
    const int tlast = olen - 1;
    const int l0  = s0q >> 2, j0 = s0q & 3;
    const int l1e = (s1q == 256) ? 63 : (s1q >> 2);
    const int j1  = s1q & 3;
    const float* base = outputs + (size_t)b * T_ * V_;
    const int*   lab  = labels + b * L_;

    // per-lane label columns (consumer lane l's odd states)
    const int cA = lab[2 * lane];         // col for state 4l+1
    const int cB = lab[2 * lane + 1];     // col for state 4l+3

    // ---------------- consumer setup (wave 0) ----------------
    float sk1 = 0.f, sk3 = 0.f;
    float v0 = 0.f, v1 = 0.f, v2 = 0.f, v3 = 0.f, vx = 0.f;  // vx: state 256 (lane63)
    int   E = 0;                                             // per-lane scale
    const bool isl0 = (lane == 0);
    if (wid == 0) {
        __builtin_amdgcn_s_setprio(3);
        sk3 = (cB != cA) ? 1.f : 0.f;
        if (lane >= 1) sk1 = (cA != lab[2 * lane - 1]) ? 1.f : 0.f;
        if (isl0) {
            v0 = exp2_fast(base[0]      * LOG2E_);       // s=0 blank
            v1 = exp2_fast(base[lab[0]] * LOG2E_);       // s=1 first label
        }
        if (tlast == 0) {
            float w0 = (j0==0)?v0:(j0==1)?v1:(j0==2)?v2:v3;
            float w1 = (s1q==256) ? vx : ((j1==0)?v0:(j1==1)?v1:(j1==2)?v2:v3);
            if (lane == l0)  { save2[0] = w0; saveE[0] = E; }
            if (lane == l1e) { save2[1] = w1; saveE[1] = E; }
        }
    } else {
        __builtin_amdgcn_s_setprio(0);
    }

    // producer reg sets (2 chunks in flight; parity-static indexing)
    f4_t A0[8], C0r[8], A1[8], C1r[8];

    // issue all 16 coalesced b128 loads for one chunk (full MLP)
    auto pload = [&](f4_t (&A)[8], f4_t (&Cc)[8], int t0) {
        const int w1 = wid - 1;
        #pragma unroll
        for (int m = 0; m < 8; ++m) {
            int t = t0 + w1 + 7 * m;
            const f4_t* rp = (const f4_t*)((t < T_) ? (base + (size_t)t * V_) : base);
            A[m]  = rp[lane];          // cols 4*lane   .. 4*lane+3
            Cc[m] = rp[lane + 64];     // cols 256+4*lane ..
        }
    };
    // LDS bounce + random-col select + pack into ring buffer bb (R4-proven)
    auto ppack = [&](int bb, f4_t (&A)[8], f4_t (&Cc)[8], int t0) {
        const int w1 = wid - 1;
        scr[w1][0][lane]      = A[0];      // conflict-free: 16B/lane contiguous
        scr[w1][0][lane + 64] = Cc[0];
        #pragma unroll
        for (int m = 1; m <= 8; ++m) {
            if (m < 8) {
                scr[w1][m & 1][lane]      = A[m];
                scr[w1][m & 1][lane + 64] = Cc[m];
            }
            int r = w1 + 7 * (m - 1);
            int t = t0 + r;
            if (t < T_) {
                float gb = bcast_first_f(A[m - 1].x);    // blank col, bit-exact
                const float* sf = (const float*)&scr[w1][(m - 1) & 1][0];
                float g1 = sf[cA];     // scattered: conflicts land producer-side
                float g3 = sf[cB];
                f4_t e;
                e.x = exp2_fast(gb * LOG2E_);
                e.y = exp2_fast(g1 * LOG2E_);
                e.z = exp2_fast(g3 * LOG2E_);
                e.w = 0.f;
                ring4[bb][r * RW4_ + lane] = e;
            }
        }
    };

    // one recursion step; e-fold scale align (bit-identical to own-shift form)
    auto step = [&](f4_t e) {
        float up1 = dpp_shr1_f(v3);           // state 4l-1 (lane0 -> 0)
        int   upE = dpp_shr1_keep_i(E, E);    // lane0 keeps own E
        int d    = upE - E;
        int mpos = (d > 0) ? d : 0;
        int sown = -mpos;
        E += mpos;
        up1 = ldx(up1, d);                    // exact; up1==0 whenever |d| huge
        float ex_ = ldx(e.x, sown);           // fold own-rescale into multipliers
        float ey_ = ldx(e.y, sown);
        float ez_ = ldx(e.z, sown);
        float n0 = (v0 + up1) * ex_;                   // even: no skip, blank col
        float n1 = fmaf(sk1, up1, v1 + v0) * ey_;      // skip from 4l-1 = up1
        float n2 = (v2 + v1) * ex_;                    // even: no skip, blank col
        float n3 = fmaf(sk3, v1, v3 + v2) * ez_;       // skip from 4l+1 = v1
        vx = (vx + v3) * ex_;                          // state 256 (blank col too)
        v0 = n0; v1 = n1; v2 = n2; v3 = n3;
    };

    auto renorm = [&]() {
        float mx = fmaxf(fmaxf(v0, v1), fmaxf(v2, v3));
        mx = fmaxf(mx, vx);
        int ex = (__float_as_int(mx) >> 23) - 126;     // 0 lanes: ex = -126
        v0 = ldx(v0, -ex); v1 = ldx(v1, -ex); v2 = ldx(v2, -ex); v3 = ldx(v3, -ex);
        vx = ldx(vx, -ex);
        E += ex;
    };

    auto consume = [&](int bb, int t0) {
        const f4_t* rp4 = &ring4[bb][lane];
        // 8-deep prefetch ring; residues constant under unroll 8
        f4_t eb8[8];
        #pragma unroll
        for (int i = 0; i < 8; ++i) eb8[i] = rp4[i * RW4_];

        bool chk = (t0 + C_ > T_) || ((unsigned)(tlast - t0) < (unsigned)C_);
        if (!chk) {
            #pragma unroll 8
            for (int r = 0; r < C_; ++r) {
                f4_t e = eb8[r & 7];
                if (r + 8 < C_) eb8[r & 7] = rp4[(r + 8) * RW4_];
                step(e);
                if ((r & 3) == 3) renorm();
            }
        } else {
            #pragma unroll 4
            for (int r = 0; r < C_; ++r) {
                int t = t0 + r;
                if (t >= T_) break;
                f4_t e = eb8[r & 7];
                if (r + 8 < C_) eb8[r & 7] = rp4[(r + 8) * RW4_];
                step(e);
                if ((r & 3) == 3) renorm();
                if (t == tlast) {
                    float w0 = (j0==0)?v0:(j0==1)?v1:(j0==2)?v2:v3;
                    float w1 = (s1q==256) ? vx : ((j1==0)?v0:(j1==1)?v1:(j1==2)?v2:v3);
                    if (lane == l0)  { save2[0] = w0; saveE[0] = E; }
                    if (lane == l1e) { save2[1] = w1; saveE[1] = E; }
                }
            }
        }
    };

    // ---------------- pipeline (chunk-level load-ahead) ----------------
    // prologue: chunk0 loaded+packed; chunk1 loaded (retires across chunk 0)
    if (wid > 0) {
        pload(A0, C0r, 1);
        ppack(0, A0, C0r, 1);
        if (NC_ > 1) pload(A1, C1r, 1 + C_);
    }
    __syncthreads();
    for (int c = 0; c < NC_; ++c) {
        if (wid > 0) {
            // issue loads for chunk c+2 first (MLP), then pack chunk c+1
            if (c + 2 < NC_) {
                if ((c + 2) & 1) pload(A1, C1r, 1 + (c + 2) * C_);
                else             pload(A0, C0r, 1 + (c + 2) * C_);
            }
            if (c + 1 < NC_) {
                if ((c + 1) & 1) ppack(1, A1, C1r, 1 + (c + 1) * C_);
                else             ppack(0, A0, C0r, 1 + (c + 1) * C_);
            }
        } else {
            consume(c & 1, 1 + c * C_);
        }
        __syncthreads();
    }

    // ---------------- fused finish: per-batch loss + last-block mean ----------
    if (tid == 0) {
        float lx = log2_fast(save2[0]) + (float)saveE[0];
        float ly = log2_fast(save2[1]) + (float)saveE[1];
        float m  = fmaxf(lx, ly);
        float lik2 = m + log2_fast(exp2_fast(lx - m) + exp2_fast(ly - m));
        float loss = -(lik2 * LN2_) / (float)ll;
        __hip_atomic_store(&losses[b], loss, __ATOMIC_RELAXED, __HIP_MEMORY_SCOPE_AGENT);
        int old = __hip_atomic_fetch_add(cnt, 1, __ATOMIC_ACQ_REL, __HIP_MEMORY_SCOPE_AGENT);
        amLast = (old == B_ - 1);
    }
    __syncthreads();
    if (amLast && wid == 0) {
        float v = __hip_atomic_load(&losses[lane], __ATOMIC_RELAXED, __HIP_MEMORY_SCOPE_AGENT);
        #pragma unroll
        for (int o = 32; o > 0; o >>= 1) v += __shfl_down(v, o);
        if (lane == 0) out[0] = v * (1.0f / B_);
    }
}

extern "C" void kernel_launch(void* const* d_in, const int* in_sizes, int n_in,
                              void* d_out, int out_size, void* d_ws, size_t ws_size,
                              hipStream_t stream) {
    const float* outputs  = (const float*)d_in[0];
    const int*   labels   = (const int*)d_in[1];
    const int*   out_lens = (const int*)d_in[2];
    const int*   lab_lens = (const int*)d_in[3];

    (void)hipMemsetAsync(d_ws, 0, 64, stream);   // zero the completion counter
    ctc_alpha_kernel<<<B_, 512, 0, stream>>>(outputs, labels, out_lens, lab_lens,
                                             (float*)d_ws, (float*)d_out);
}